// Round 1
// baseline (1006.988 us; speedup 1.0000x reference)
//
#include <hip/hip_runtime.h>

// LSTMClassifier: B=2048, T=500, H1=128, H2=64, D_IN=1, FC 64->128->4.
//
// Strategy (round 1):
//  - D_IN==1 => LSTM1 input projection collapses to xg1 = x*u1 + v1 (u1,v1
//    computed per-lane once at kernel start; no input GEMM).
//  - Fully fused persistent scan: one block owns BM=16 batch rows for all
//    500 steps; LSTM1+LSTM2 both advanced per step (no (B,T,128) HBM
//    intermediate).
//  - Recurrent matmuls via v_mfma_f32_16x16x32_bf16. Weights held as bf16
//    B-fragments in REGISTERS (fp32 weights in LDS don't fit: Whh1=256KB).
//    Gate rows permuted per-wave ([i(32)|f(32)|g(32)|o(32)] slice) so the
//    i/f/g/o combine is lane-local in the C/D fragment layout.
//  - h1/h2 state: double-buffered bf16 in LDS (+8 pad -> 2-way bank alias,
//    free). c1/c2 state: fp32 in registers. x: staged once to LDS.
//  - 2 barriers/step (publish h1, publish h2).
//  - FC head (64->128 relu ->4) done per-block in fp32 after the scan.

#define B_   2048
#define T_   500
#define BM   16
#define NBLK (B_ / BM)   // 128 blocks

typedef __attribute__((ext_vector_type(8))) short bf16x8;   // 8 bf16 = 4 VGPR
typedef __attribute__((ext_vector_type(4))) float f32x4;

static __device__ __forceinline__ short f2bf(float f) {
  // round-to-nearest-even bf16 (values here are well-behaved, no NaN path)
  unsigned u = __builtin_bit_cast(unsigned, f);
  u = (u + 0x7fffu + ((u >> 16) & 1u)) >> 16;
  return (short)u;
}
static __device__ __forceinline__ float sigm(float x) {
  return __builtin_amdgcn_rcpf(1.0f + __expf(-x));
}
static __device__ __forceinline__ float tanh_(float x) {
  // tanh(x) = 1 - 2/(exp(2x)+1); saturates correctly at +/-inf
  return 1.0f - 2.0f * __builtin_amdgcn_rcpf(1.0f + __expf(2.0f * x));
}

__global__ __launch_bounds__(256, 1)
void lstm_fused(const float* __restrict__ X,     // (B,1,T)
                const float* __restrict__ Wp,    // (128,1)
                const float* __restrict__ bp,    // (128)
                const float* __restrict__ Wih1,  // (512,128)
                const float* __restrict__ Whh1,  // (512,128)
                const float* __restrict__ bih1,  // (512)
                const float* __restrict__ bhh1,  // (512)
                const float* __restrict__ Wih2,  // (256,128)
                const float* __restrict__ Whh2,  // (256,64)
                const float* __restrict__ bih2,  // (256)
                const float* __restrict__ bhh2,  // (256)
                const float* __restrict__ W1,    // (128,64)
                const float* __restrict__ b1,    // (128)
                const float* __restrict__ W2,    // (4,128)
                const float* __restrict__ b2,    // (4)
                float* __restrict__ Out) {       // (B,4)
  // LDS: 8704 + 4608 + 32000 + 4096 + 8448 = 57856 B (< 64KB static limit)
  __shared__ short h1b[2][16][136];  // h1 state, bf16, +8 pad (2-way alias ok)
  __shared__ short h2b[2][16][72];   // h2 state, bf16, +8 pad
  __shared__ float xs[16][500];      // staged x rows for this block
  __shared__ float h2f[16][64];      // final h2, fp32, for FC head
  __shared__ float fc1s[16][132];    // fc1 activations, +4 pad

  const int tid = threadIdx.x;
  const int ln = tid & 63;
  const int wv = tid >> 6;     // wave 0..3
  const int cl = ln & 15;      // fragment column / A-row lane
  const int kg = ln >> 4;      // K-group 0..3
  const int r0 = blockIdx.x * BM;

  // ---------------- one-time setup ----------------
  // Weight fragments. Wave wv owns LSTM1 units [32wv,32wv+32) and LSTM2
  // units [16wv,16wv+16), gate-slice order [i|f|g|o].
  bf16x8 W1f[8][4];   // Whh1^T slice: 8 N-frags x 4 K-frags  (128 VGPR)
  bf16x8 W2if[4][4];  // Wih2^T slice: 4 N-frags x 4 K-frags  (64 VGPR)
  bf16x8 W2hf[4][2];  // Whh2^T slice: 4 N-frags x 2 K-frags  (32 VGPR)
  float u1v[8], v1v[8], b2v[4];

#pragma unroll
  for (int n1 = 0; n1 < 8; ++n1) {
    const int p = n1 * 16 + cl;                       // gate position in slice
    const int row = (p >> 5) * 128 + 32 * wv + (p & 31);  // original Whh1 row
    // u1[row], v1[row]: collapse of input projection (D_IN=1)
    float u = 0.f, vv = bih1[row] + bhh1[row];
    const float4* Wi4 = (const float4*)(Wih1 + row * 128);
    const float4* Wp4 = (const float4*)Wp;
    const float4* bp4 = (const float4*)bp;
#pragma unroll 4
    for (int d = 0; d < 32; ++d) {
      float4 a = Wi4[d], pw = Wp4[d], qb = bp4[d];
      u  += a.x*pw.x + a.y*pw.y + a.z*pw.z + a.w*pw.w;
      vv += a.x*qb.x + a.y*qb.y + a.z*qb.z + a.w*qb.w;
    }
    u1v[n1] = u; v1v[n1] = vv;
#pragma unroll
    for (int kf = 0; kf < 4; ++kf) {
      // B-frag: lane ln, elem e -> B[k][n] = Whh1[row][k], k = kf*32+kg*8+e
      const float4* s4 = (const float4*)(Whh1 + row * 128 + kf * 32 + kg * 8);
      float4 a0 = s4[0], a1 = s4[1];
      bf16x8 fr;
      fr[0]=f2bf(a0.x); fr[1]=f2bf(a0.y); fr[2]=f2bf(a0.z); fr[3]=f2bf(a0.w);
      fr[4]=f2bf(a1.x); fr[5]=f2bf(a1.y); fr[6]=f2bf(a1.z); fr[7]=f2bf(a1.w);
      W1f[n1][kf] = fr;
    }
  }
#pragma unroll
  for (int n2 = 0; n2 < 4; ++n2) {
    const int row = n2 * 64 + 16 * wv + cl;   // gate-type n2, unit 16wv+cl
    b2v[n2] = bih2[row] + bhh2[row];
#pragma unroll
    for (int kf = 0; kf < 4; ++kf) {
      const float4* s4 = (const float4*)(Wih2 + row * 128 + kf * 32 + kg * 8);
      float4 a0 = s4[0], a1 = s4[1];
      bf16x8 fr;
      fr[0]=f2bf(a0.x); fr[1]=f2bf(a0.y); fr[2]=f2bf(a0.z); fr[3]=f2bf(a0.w);
      fr[4]=f2bf(a1.x); fr[5]=f2bf(a1.y); fr[6]=f2bf(a1.z); fr[7]=f2bf(a1.w);
      W2if[n2][kf] = fr;
    }
#pragma unroll
    for (int kf = 0; kf < 2; ++kf) {
      const float4* s4 = (const float4*)(Whh2 + row * 64 + kf * 32 + kg * 8);
      float4 a0 = s4[0], a1 = s4[1];
      bf16x8 fr;
      fr[0]=f2bf(a0.x); fr[1]=f2bf(a0.y); fr[2]=f2bf(a0.z); fr[3]=f2bf(a0.w);
      fr[4]=f2bf(a1.x); fr[5]=f2bf(a1.y); fr[6]=f2bf(a1.z); fr[7]=f2bf(a1.w);
      W2hf[n2][kf] = fr;
    }
  }

  // zero the t=0 "previous" buffers (index 1; t=0 has cur=0, prv=1)
  for (int i = tid; i < 16 * 136; i += 256) ((short*)h1b[1])[i] = 0;
  for (int i = tid; i < 16 * 72;  i += 256) ((short*)h2b[1])[i] = 0;
  // stage x for this block's 16 rows
  for (int r = 0; r < 16; ++r)
    for (int cc = tid; cc < T_; cc += 256)
      xs[r][cc] = X[(size_t)(r0 + r) * T_ + cc];
  __syncthreads();

  float c1s[2][4] = {{0.f,0.f,0.f,0.f},{0.f,0.f,0.f,0.f}};  // c1 per (set,reg)
  float c2s[4]    = {0.f,0.f,0.f,0.f};                       // c2 per reg

  // ---------------- the scan ----------------
  for (int t = 0; t < T_; ++t) {
    const int cur = t & 1, prv = cur ^ 1;

    // P1: G1 = x*u1 + v1 + h1_prev @ Whh1^T   (wave's 128-gate slice)
    bf16x8 a1[4];
#pragma unroll
    for (int kf = 0; kf < 4; ++kf)
      a1[kf] = *(const bf16x8*)&h1b[prv][cl][kf * 32 + kg * 8];
    float xr[4];
#pragma unroll
    for (int e = 0; e < 4; ++e) xr[e] = xs[kg * 4 + e][t];

    f32x4 acc[8];
#pragma unroll
    for (int n1 = 0; n1 < 8; ++n1) {
      f32x4 a;
#pragma unroll
      for (int e = 0; e < 4; ++e) a[e] = xr[e] * u1v[n1] + v1v[n1];
#pragma unroll
      for (int kf = 0; kf < 4; ++kf)
        a = __builtin_amdgcn_mfma_f32_16x16x32_bf16(a1[kf], W1f[n1][kf], a, 0, 0, 0);
      acc[n1] = a;
    }

    // P2: lane-local gate combine; units setA=32wv+cl (frags 0,2,4,6),
    //     setB=32wv+16+cl (frags 1,3,5,7). rows = kg*4+e.
#pragma unroll
    for (int s = 0; s < 2; ++s) {
      const int col = 32 * wv + 16 * s + cl;
#pragma unroll
      for (int e = 0; e < 4; ++e) {
        float ig = sigm(acc[s][e]);
        float fg = sigm(acc[s + 2][e]);
        float gg = tanh_(acc[s + 4][e]);
        float og = sigm(acc[s + 6][e]);
        float cn = fg * c1s[s][e] + ig * gg;
        c1s[s][e] = cn;
        h1b[cur][kg * 4 + e][col] = f2bf(og * tanh_(cn));
      }
    }
    __syncthreads();   // publish h1_t

    // P3: G2 = b2 + h1_t @ Wih2^T + h2_prev @ Whh2^T  (wave's 64-gate slice)
    bf16x8 ah[4], ag[2];
#pragma unroll
    for (int kf = 0; kf < 4; ++kf)
      ah[kf] = *(const bf16x8*)&h1b[cur][cl][kf * 32 + kg * 8];
#pragma unroll
    for (int kf = 0; kf < 2; ++kf)
      ag[kf] = *(const bf16x8*)&h2b[prv][cl][kf * 32 + kg * 8];

    f32x4 acc2[4];
#pragma unroll
    for (int n2 = 0; n2 < 4; ++n2) {
      f32x4 a = {b2v[n2], b2v[n2], b2v[n2], b2v[n2]};
#pragma unroll
      for (int kf = 0; kf < 4; ++kf)
        a = __builtin_amdgcn_mfma_f32_16x16x32_bf16(ah[kf], W2if[n2][kf], a, 0, 0, 0);
#pragma unroll
      for (int kf = 0; kf < 2; ++kf)
        a = __builtin_amdgcn_mfma_f32_16x16x32_bf16(ag[kf], W2hf[n2][kf], a, 0, 0, 0);
      acc2[n2] = a;
    }

    // P4: LSTM2 combine; unit j2 = 16wv+cl, frag n2 = gate type directly.
    {
      const int j2 = 16 * wv + cl;
#pragma unroll
      for (int e = 0; e < 4; ++e) {
        float ig = sigm(acc2[0][e]);
        float fg = sigm(acc2[1][e]);
        float gg = tanh_(acc2[2][e]);
        float og = sigm(acc2[3][e]);
        float cn = fg * c2s[e] + ig * gg;
        c2s[e] = cn;
        float hv = og * tanh_(cn);
        h2b[cur][kg * 4 + e][j2] = f2bf(hv);
        if (t == T_ - 1) h2f[kg * 4 + e][j2] = hv;   // fp32 copy for FC head
      }
    }
    __syncthreads();   // publish h2_t
  }

  // ---------------- FC head (fp32) ----------------
  // fc1: (16 x 64) @ (64 x 128) + b1, relu
  {
    const int u = tid & 127, rh = tid >> 7;
    float a8[8];
#pragma unroll
    for (int e = 0; e < 8; ++e) a8[e] = b1[u];
    for (int k = 0; k < 64; ++k) {
      float wv1 = W1[u * 64 + k];
#pragma unroll
      for (int e = 0; e < 8; ++e) a8[e] += h2f[rh * 8 + e][k] * wv1;
    }
#pragma unroll
    for (int e = 0; e < 8; ++e) fc1s[rh * 8 + e][u] = fmaxf(a8[e], 0.f);
  }
  __syncthreads();
  // fc2: (16 x 128) @ (128 x 4) + b2
  if (tid < 64) {
    const int r = tid >> 2, cls = tid & 3;
    float a = b2[cls];
    for (int k = 0; k < 128; ++k) a += fc1s[r][k] * W2[cls * 128 + k];
    Out[(size_t)(r0 + r) * 4 + cls] = a;
  }
}

extern "C" void kernel_launch(void* const* d_in, const int* in_sizes, int n_in,
                              void* d_out, int out_size, void* d_ws, size_t ws_size,
                              hipStream_t stream) {
  const float* X    = (const float*)d_in[0];
  const float* Wp   = (const float*)d_in[1];
  const float* bp   = (const float*)d_in[2];
  const float* Wih1 = (const float*)d_in[3];
  const float* Whh1 = (const float*)d_in[4];
  const float* bih1 = (const float*)d_in[5];
  const float* bhh1 = (const float*)d_in[6];
  const float* Wih2 = (const float*)d_in[7];
  const float* Whh2 = (const float*)d_in[8];
  const float* bih2 = (const float*)d_in[9];
  const float* bhh2 = (const float*)d_in[10];
  const float* W1   = (const float*)d_in[11];
  const float* b1   = (const float*)d_in[12];
  const float* W2   = (const float*)d_in[13];
  const float* b2   = (const float*)d_in[14];
  float* Out = (float*)d_out;

  hipLaunchKernelGGL(lstm_fused, dim3(NBLK), dim3(256), 0, stream,
                     X, Wp, bp, Wih1, Whh1, bih1, bhh1,
                     Wih2, Whh2, bih2, bhh2, W1, b1, W2, b2, Out);
}

// Round 2
// 671.955 us; speedup vs baseline: 1.4986x; 1.4986x over previous
//
#include <hip/hip_runtime.h>

// LSTMClassifier: B=2048, T=500, H1=128, H2=64, D_IN=1, FC 64->128->4.
//
// Round 2 changes vs round 1 (1007 us, MfmaUtil 9%, VALUBusy 27%, occ 6%):
//  - BM=8, 256 blocks -> all 256 CUs active (was 128). Trans work per CU
//    halves; MFMA per block unchanged (M=16 tile half-wasted, MFMA is cheap).
//  - 512 threads = 8 waves (2/SIMD). LSTM1 split across all 8 waves
//    (frag n = gate type, units 16wv..16wv+16, 16 MFMA/wave). LSTM2 on
//    waves 0-3 only (unit = 16wv+cl, frag = type).
//  - Combine balancing: only kg<2 lanes hold real C rows at BM=8; shfl_xor
//    lane^32 moves rows {2,3} of each 4-row group to kg>=2 lanes so all 64
//    lanes do 2 combines (exec-masked trans lanes are not free).
//  - Cell math: sigm(a)*tanh(b) = (e^{2b}-1)/((1+e^{-a})(1+e^{2b})) -> 5 exp
//    + 3 rcp per unit (was 10 trans). Exact algebra, no approximation.
//  - x read from global with 1-step prefetch (8x500x4B slice is L1-resident);
//    Whh2 as pre-permuted bf16 fragments in LDS (saves 32 VGPR).
//  - A-fragment reads hoisted across barriers (h1[t] frags serve both ph2(t)
//    and ph1(t+1)); h2 frags issued at top of step, consumed in ph2.

#define B_   2048
#define T_   500
#define BM   8
#define NBLK (B_ / BM)   // 256 blocks = 1 per CU

typedef __attribute__((ext_vector_type(8))) short bf16x8;   // 8 bf16 = 4 VGPR
typedef __attribute__((ext_vector_type(4))) float f32x4;

static __device__ __forceinline__ short f2bf(float f) {
  unsigned u = __builtin_bit_cast(unsigned, f);
  u = (u + 0x7fffu + ((u >> 16) & 1u)) >> 16;   // RNE
  return (short)u;
}

// c' = sigm(gf)*c + sigm(gi)*tanh(gg);  h = sigm(go)*tanh(c')
// using sigm(a)*tanh(b) = (e^{2b}-1) / ((1+e^{-a})(1+e^{2b})): 5 exp + 3 rcp.
static __device__ __forceinline__ float lstm_cell(float gi, float gf, float gg,
                                                  float go, float& c) {
  float Ei = __expf(-gi);
  float Eg = __expf(2.f * gg);
  float p  = (Eg - 1.f) * __builtin_amdgcn_rcpf((1.f + Ei) * (1.f + Eg));
  float Ef = __expf(-gf);
  c = __builtin_amdgcn_rcpf(1.f + Ef) * c + p;
  float Eo = __expf(-go);
  float Ec = __expf(2.f * c);
  return (Ec - 1.f) * __builtin_amdgcn_rcpf((1.f + Eo) * (1.f + Ec));
}

__global__ __launch_bounds__(512, 2)
void lstm_fused(const float* __restrict__ X,     // (B,1,T)
                const float* __restrict__ Wp,    // (128,1)
                const float* __restrict__ bp,    // (128)
                const float* __restrict__ Wih1,  // (512,128)
                const float* __restrict__ Whh1,  // (512,128)
                const float* __restrict__ bih1,  // (512)
                const float* __restrict__ bhh1,  // (512)
                const float* __restrict__ Wih2,  // (256,128)
                const float* __restrict__ Whh2,  // (256,64)
                const float* __restrict__ bih2,  // (256)
                const float* __restrict__ bhh2,  // (256)
                const float* __restrict__ W1,    // (128,64)
                const float* __restrict__ b1,    // (128)
                const float* __restrict__ W2,    // (4,128)
                const float* __restrict__ b2,    // (4)
                float* __restrict__ Out) {       // (B,4)
  __shared__ short h1b[2][16][136];  // h1 state bf16 dbuf; rows 8..15 stay 0
  __shared__ short h2b[2][16][72];   // h2 state bf16 dbuf
  __shared__ short w2h[32][512];     // Whh2 pre-permuted B-frags (32 KB)
  __shared__ float h2f[8][64];       // final h2 fp32 for FC head
  __shared__ float fc1s[8][132];     // fc1 activations (+4 pad)

  const int tid = threadIdx.x;
  const int ln = tid & 63;
  const int wv = tid >> 6;     // wave 0..7
  const int cl = ln & 15;      // fragment column / A-row
  const int kg = ln >> 4;      // K-group 0..3
  const int li = cl * 4 + kg;  // w2h lane slot (even bank spread for b128)
  const int r0 = blockIdx.x * BM;

  // ---------------- one-time setup ----------------
  // LSTM1: wave wv owns units [16wv,16wv+16), frag n = gate type.
  bf16x8 W1f[4][4];
  float u1v[4], v1v[4];
#pragma unroll
  for (int n = 0; n < 4; ++n) {
    const int R = n * 128 + 16 * wv + cl;   // original Whh1/Wih1 row
    float u = 0.f, vv = bih1[R] + bhh1[R];
    const float4* Wi4 = (const float4*)(Wih1 + R * 128);
    const float4* Wp4 = (const float4*)Wp;
    const float4* bp4 = (const float4*)bp;
#pragma unroll 4
    for (int d = 0; d < 32; ++d) {
      float4 a = Wi4[d], pw = Wp4[d], qb = bp4[d];
      u  += a.x*pw.x + a.y*pw.y + a.z*pw.z + a.w*pw.w;
      vv += a.x*qb.x + a.y*qb.y + a.z*qb.z + a.w*qb.w;
    }
    u1v[n] = u; v1v[n] = vv;
#pragma unroll
    for (int kf = 0; kf < 4; ++kf) {
      const float4* s4 = (const float4*)(Whh1 + R * 128 + kf * 32 + kg * 8);
      float4 a0 = s4[0], a1 = s4[1];
      bf16x8 fr;
      fr[0]=f2bf(a0.x); fr[1]=f2bf(a0.y); fr[2]=f2bf(a0.z); fr[3]=f2bf(a0.w);
      fr[4]=f2bf(a1.x); fr[5]=f2bf(a1.y); fr[6]=f2bf(a1.z); fr[7]=f2bf(a1.w);
      W1f[n][kf] = fr;
    }
  }

  // LSTM2 (waves 0-3): unit = 16wv+cl, frag n2 = gate type.
  bf16x8 W2if[4][4];
  float b2v[4] = {0.f, 0.f, 0.f, 0.f};
  if (wv < 4) {
#pragma unroll
    for (int n2 = 0; n2 < 4; ++n2) {
      const int R = n2 * 64 + 16 * wv + cl;
      b2v[n2] = bih2[R] + bhh2[R];
#pragma unroll
      for (int kf = 0; kf < 4; ++kf) {
        const float4* s4 = (const float4*)(Wih2 + R * 128 + kf * 32 + kg * 8);
        float4 a0 = s4[0], a1 = s4[1];
        bf16x8 fr;
        fr[0]=f2bf(a0.x); fr[1]=f2bf(a0.y); fr[2]=f2bf(a0.z); fr[3]=f2bf(a0.w);
        fr[4]=f2bf(a1.x); fr[5]=f2bf(a1.y); fr[6]=f2bf(a1.z); fr[7]=f2bf(a1.w);
        W2if[n2][kf] = fr;
      }
      // Whh2 B-frags -> LDS (pre-permuted so the per-step read is a b128)
#pragma unroll
      for (int kf = 0; kf < 2; ++kf) {
        const float4* s4 = (const float4*)(Whh2 + R * 64 + kf * 32 + kg * 8);
        float4 a0 = s4[0], a1 = s4[1];
        short* dst = &w2h[(wv * 4 + n2) * 2 + kf][li * 8];
        dst[0]=f2bf(a0.x); dst[1]=f2bf(a0.y); dst[2]=f2bf(a0.z); dst[3]=f2bf(a0.w);
        dst[4]=f2bf(a1.x); dst[5]=f2bf(a1.y); dst[6]=f2bf(a1.z); dst[7]=f2bf(a1.w);
      }
    }
  }

  // zero both h-state buffers (rows 8..15 must stay zero forever)
  for (int i = tid; i < 2 * 16 * 136; i += 512) ((short*)h1b)[i] = 0;
  for (int i = tid; i < 2 * 16 * 72;  i += 512) ((short*)h2b)[i] = 0;
  __syncthreads();

  // persistent per-lane state
  bf16x8 a1[4];                         // h1[t-1] A-frags
#pragma unroll
  for (int kf = 0; kf < 4; ++kf) a1[kf] = (bf16x8)0;
  bf16x8 ag[2];                         // h2[t-1] A-frags (waves 0-3)
  ag[0] = (bf16x8)0; ag[1] = (bf16x8)0;
  float c1a = 0.f, c1b = 0.f, c2a = 0.f, c2b = 0.f;

  // this lane's two (row) slots after redistribution
  const int rA = (kg < 2) ? kg * 4 : (kg - 2) * 4 + 2;
  const int rB = rA + 1;
  const int uu = 16 * wv + cl;          // unit owned (both LSTMs)

  float xr[4];                          // x for rows kg*4+e (kg<2 real)
#pragma unroll
  for (int e = 0; e < 4; ++e)
    xr[e] = (kg < 2) ? X[(size_t)(r0 + kg * 4 + e) * T_ + 0] : 0.f;

  // ---------------- the scan ----------------
  for (int t = 0; t < T_; ++t) {
    const int cur = t & 1, prv = cur ^ 1;

    // issue h2[t-1] frag reads early (published at last barrier)
    if (wv < 4) {
#pragma unroll
      for (int kf = 0; kf < 2; ++kf)
        ag[kf] = *(const bf16x8*)&h2b[prv][cl][kf * 32 + kg * 8];
    }

    // ph1: G1 = x*u1 + v1 + h1[t-1] @ Whh1^T  (all 8 waves, 16 MFMA)
    f32x4 acc[4];
#pragma unroll
    for (int n = 0; n < 4; ++n) {
      f32x4 a;
#pragma unroll
      for (int e = 0; e < 4; ++e) a[e] = xr[e] * u1v[n] + v1v[n];
#pragma unroll
      for (int kf = 0; kf < 4; ++kf)
        a = __builtin_amdgcn_mfma_f32_16x16x32_bf16(a1[kf], W1f[n][kf], a, 0, 0, 0);
      acc[n] = a;
    }

    // redistribute rows {2,3} of each group to kg>=2 lanes, combine, write
    {
      float gA[4], gB[4];
#pragma unroll
      for (int n = 0; n < 4; ++n) {
        float s2 = __shfl_xor(acc[n][2], 32);
        float s3 = __shfl_xor(acc[n][3], 32);
        gA[n] = (kg < 2) ? acc[n][0] : s2;
        gB[n] = (kg < 2) ? acc[n][1] : s3;
      }
      float hA = lstm_cell(gA[0], gA[1], gA[2], gA[3], c1a);
      float hB = lstm_cell(gB[0], gB[1], gB[2], gB[3], c1b);
      h1b[cur][rA][uu] = f2bf(hA);
      h1b[cur][rB][uu] = f2bf(hB);
    }
    __syncthreads();   // B: h1[t] published

    // h1[t] frags: serve ph2(t) AND ph1(t+1)
#pragma unroll
    for (int kf = 0; kf < 4; ++kf)
      a1[kf] = *(const bf16x8*)&h1b[cur][cl][kf * 32 + kg * 8];

    // prefetch x for t+1
    if (t + 1 < T_ && kg < 2) {
#pragma unroll
      for (int e = 0; e < 4; ++e)
        xr[e] = X[(size_t)(r0 + kg * 4 + e) * T_ + (t + 1)];
    }

    // ph2: G2 = b2 + h1[t] @ Wih2^T + h2[t-1] @ Whh2^T  (waves 0-3)
    if (wv < 4) {
      f32x4 acc2[4];
#pragma unroll
      for (int n2 = 0; n2 < 4; ++n2) {
        f32x4 a = {b2v[n2], b2v[n2], b2v[n2], b2v[n2]};
        bf16x8 w0 = *(const bf16x8*)&w2h[(wv * 4 + n2) * 2 + 0][li * 8];
        bf16x8 w1 = *(const bf16x8*)&w2h[(wv * 4 + n2) * 2 + 1][li * 8];
        a = __builtin_amdgcn_mfma_f32_16x16x32_bf16(ag[0], w0, a, 0, 0, 0);
        a = __builtin_amdgcn_mfma_f32_16x16x32_bf16(ag[1], w1, a, 0, 0, 0);
#pragma unroll
        for (int kf = 0; kf < 4; ++kf)
          a = __builtin_amdgcn_mfma_f32_16x16x32_bf16(a1[kf], W2if[n2][kf], a, 0, 0, 0);
        acc2[n2] = a;
      }
      float gA[4], gB[4];
#pragma unroll
      for (int n2 = 0; n2 < 4; ++n2) {
        float s2 = __shfl_xor(acc2[n2][2], 32);
        float s3 = __shfl_xor(acc2[n2][3], 32);
        gA[n2] = (kg < 2) ? acc2[n2][0] : s2;
        gB[n2] = (kg < 2) ? acc2[n2][1] : s3;
      }
      float hA = lstm_cell(gA[0], gA[1], gA[2], gA[3], c2a);
      float hB = lstm_cell(gB[0], gB[1], gB[2], gB[3], c2b);
      h2b[cur][rA][uu] = f2bf(hA);
      h2b[cur][rB][uu] = f2bf(hB);
      if (t == T_ - 1) { h2f[rA][uu] = hA; h2f[rB][uu] = hB; }
    }
    __syncthreads();   // A(t+1): h2[t] published
  }

  // ---------------- FC head (fp32) ----------------
  // fc1: (8 x 64) @ (64 x 128) + b1, relu
  {
    const int u = tid & 127, r2 = tid >> 7;   // r2 in 0..3 -> rows 2r2, 2r2+1
    float a0 = b1[u], a1f = b1[u];
    for (int k = 0; k < 64; ++k) {
      float w = W1[u * 64 + k];
      a0  += h2f[r2 * 2 + 0][k] * w;
      a1f += h2f[r2 * 2 + 1][k] * w;
    }
    fc1s[r2 * 2 + 0][u] = fmaxf(a0, 0.f);
    fc1s[r2 * 2 + 1][u] = fmaxf(a1f, 0.f);
  }
  __syncthreads();
  // fc2: (8 x 128) @ (128 x 4) + b2
  if (tid < 32) {
    const int r = tid >> 2, cls = tid & 3;
    float a = b2[cls];
    for (int k = 0; k < 128; ++k) a += fc1s[r][k] * W2[cls * 128 + k];
    Out[(size_t)(r0 + r) * 4 + cls] = a;
  }
}

extern "C" void kernel_launch(void* const* d_in, const int* in_sizes, int n_in,
                              void* d_out, int out_size, void* d_ws, size_t ws_size,
                              hipStream_t stream) {
  const float* X    = (const float*)d_in[0];
  const float* Wp   = (const float*)d_in[1];
  const float* bp   = (const float*)d_in[2];
  const float* Wih1 = (const float*)d_in[3];
  const float* Whh1 = (const float*)d_in[4];
  const float* bih1 = (const float*)d_in[5];
  const float* bhh1 = (const float*)d_in[6];
  const float* Wih2 = (const float*)d_in[7];
  const float* Whh2 = (const float*)d_in[8];
  const float* bih2 = (const float*)d_in[9];
  const float* bhh2 = (const float*)d_in[10];
  const float* W1   = (const float*)d_in[11];
  const float* b1   = (const float*)d_in[12];
  const float* W2   = (const float*)d_in[13];
  const float* b2   = (const float*)d_in[14];
  float* Out = (float*)d_out;

  hipLaunchKernelGGL(lstm_fused, dim3(NBLK), dim3(512), 0, stream,
                     X, Wp, bp, Wih1, Whh1, bih1, bhh1,
                     Wih2, Whh2, bih2, bhh2, W1, b1, W2, b2, Out);
}